// Round 2
// baseline (3003.582 us; speedup 1.0000x reference)
//
#include <hip/hip_runtime.h>

#define BN 256   // B*N
#define D  2048
#define C  256
#define E  128
#define M  4096
#define V  10

// ---------------------------------------------------------------------------
// K1: xp[c][bn][e] = sum_d emb[bn][d] * proj[c][d][e]
// grid (2 bn-tiles, 256 c), 256 threads, tile 128x128, K chunks of 32,
// thread tile 8x8.
// v2: double-buffered LDS (2x32KB) + register prefetch of the next chunk
// issued under the current chunk's FMA block; ONE barrier per chunk
// (write buf -> sync -> prefetch next -> compute buf).
// ---------------------------------------------------------------------------
__global__ __launch_bounds__(256) void k1_xp(const float* __restrict__ emb,
                                             const float* __restrict__ proj,
                                             float* __restrict__ xp) {
  const int c   = blockIdx.y;
  const int bn0 = blockIdx.x * 128;
  const int tid = threadIdx.x;
  const int ty  = tid >> 4;   // 0..15 row group
  const int tx  = tid & 15;   // 0..15 col group

  __shared__ __align__(16) float As[2][32][128];  // [buf][k][row] (transposed)
  __shared__ __align__(16) float Bs[2][32][128];  // [buf][k][e]

  float acc[8][8];
#pragma unroll
  for (int i = 0; i < 8; ++i)
#pragma unroll
    for (int j = 0; j < 8; ++j) acc[i][j] = 0.0f;

  const int srow = tid >> 1;          // 0..127 (A stage row)
  const int skof = (tid & 1) * 16;    // 0/16   (A stage k offset)
  const int brow = tid >> 3;          // 0..31  (B stage k row)
  const int beof = (tid & 7) * 16;    // B stage e offset

  const float* embp  = emb + (size_t)(bn0 + srow) * D + skof;
  const float* projp = proj + (size_t)c * D * E + (size_t)brow * E + beof;

  float4 ra[4], rb[4];
#pragma unroll
  for (int q = 0; q < 4; ++q) {
    ra[q] = *(const float4*)(embp + q * 4);
    rb[q] = *(const float4*)(projp + q * 4);
  }

#define K1_STEP(BUF, KK)                                                      \
  {                                                                           \
    _Pragma("unroll")                                                         \
    for (int q = 0; q < 4; ++q) {                                             \
      As[BUF][skof + q * 4 + 0][srow] = ra[q].x;                              \
      As[BUF][skof + q * 4 + 1][srow] = ra[q].y;                              \
      As[BUF][skof + q * 4 + 2][srow] = ra[q].z;                              \
      As[BUF][skof + q * 4 + 3][srow] = ra[q].w;                              \
      *(float4*)&Bs[BUF][brow][beof + q * 4] = rb[q];                         \
    }                                                                         \
    __syncthreads();                                                          \
    if ((KK) + 32 < D) {                                                      \
      _Pragma("unroll")                                                       \
      for (int q = 0; q < 4; ++q) {                                           \
        ra[q] = *(const float4*)(embp + (KK) + 32 + q * 4);                   \
        rb[q] = *(const float4*)(projp + (size_t)((KK) + 32) * E + q * 4);    \
      }                                                                       \
    }                                                                         \
    _Pragma("unroll")                                                         \
    for (int k = 0; k < 32; ++k) {                                            \
      float a[8], b[8];                                                       \
      *(float4*)&a[0] = *(const float4*)&As[BUF][k][ty * 8];                  \
      *(float4*)&a[4] = *(const float4*)&As[BUF][k][ty * 8 + 4];              \
      *(float4*)&b[0] = *(const float4*)&Bs[BUF][k][tx * 8];                  \
      *(float4*)&b[4] = *(const float4*)&Bs[BUF][k][tx * 8 + 4];              \
      _Pragma("unroll")                                                       \
      for (int i = 0; i < 8; ++i)                                             \
        _Pragma("unroll")                                                     \
        for (int j = 0; j < 8; ++j) acc[i][j] = fmaf(a[i], b[j], acc[i][j]);  \
    }                                                                         \
  }

  for (int k0 = 0; k0 < D; k0 += 64) {
    K1_STEP(0, k0)
    K1_STEP(1, k0 + 32)
  }
#undef K1_STEP

  // write xp[c][bn][e], coalesced float4
#pragma unroll
  for (int i = 0; i < 8; ++i) {
    float* op = xp + ((size_t)c * BN + bn0 + ty * 8 + i) * E + tx * 8;
    *(float4*)op       = make_float4(acc[i][0], acc[i][1], acc[i][2], acc[i][3]);
    *(float4*)(op + 4) = make_float4(acc[i][4], acc[i][5], acc[i][6], acc[i][7]);
  }
}

// ---------------------------------------------------------------------------
// K2: for each (c, bn): idx[c][bn] = argmin_m ( e_sq[c][m] - 2 * dots[c][bn][m] )
// grid (4 bn-tiles, 256 c), 256 threads.
// v2: m-tile 128 (was 64), thread tile 4x8 (was 4x4) -> 32 FMA per 3
// ds_read_b128 (was 16 per 2). Codebook streamed in 32-k chunks with
// register prefetch of the next chunk issued under the current chunk's
// compute; e_sq accumulated during staging (2 partials/row).
// LDS = 32K(As) + 16K(Bs) + 1K(esq) = 50176 B -> 3 blocks/CU.
// First-index argmin semantics preserved.
// ---------------------------------------------------------------------------
__global__ __launch_bounds__(256) void k2_argmin(const float* __restrict__ xp,
                                                 const float* __restrict__ cb,
                                                 int* __restrict__ idxo) {
  const int c   = blockIdx.y;
  const int bn0 = blockIdx.x * 64;
  const int tid = threadIdx.x;
  const int ty  = tid >> 4;   // 0..15 -> rows ty*4..+3
  const int tx  = tid & 15;   // 0..15 -> cols tx*8..+7

  __shared__ __align__(16) float As[128][64];   // [e][row] (transposed xp)
  __shared__ __align__(16) float Bs[32][128];   // [k_local][m]
  __shared__ float esqp[128][2];

  // stage As: xp[c][bn0+row][*] transposed (once, reused for all m-tiles)
  {
    const int row = tid >> 2;           // 0..63
    const int eof = (tid & 3) * 32;
    const float* p = xp + ((size_t)c * BN + bn0 + row) * E + eof;
#pragma unroll
    for (int q = 0; q < 8; ++q) {
      float4 v = *(const float4*)(p + q * 4);
      As[eof + q * 4 + 0][row] = v.x;
      As[eof + q * 4 + 1][row] = v.y;
      As[eof + q * 4 + 2][row] = v.z;
      As[eof + q * 4 + 3][row] = v.w;
    }
  }

  float bestv[4];
  int   besti[4];
#pragma unroll
  for (int i = 0; i < 4; ++i) { bestv[i] = 3.4e38f; besti[i] = 0; }

  const int sm  = tid >> 1;      // 0..127: m row staged by this thread
  const int par = tid & 1;       // 0/1 -> 16-float half of each 32-k chunk
  const float* cbp = cb + ((size_t)c * M + sm) * E + par * 16;

  float4 rb[4];
  // preload chunk t=0 (mt=0, kc=0)
#pragma unroll
  for (int q = 0; q < 4; ++q) rb[q] = *(const float4*)(cbp + q * 4);

  for (int mt = 0; mt < M / 128; ++mt) {
    float acc[4][8];
#pragma unroll
    for (int i = 0; i < 4; ++i)
#pragma unroll
      for (int j = 0; j < 8; ++j) acc[i][j] = 0.0f;
    float esqa = 0.0f;

    for (int kc = 0; kc < 4; ++kc) {
      __syncthreads();   // prior chunk's Bs reads done (also covers As stage)
      // stage chunk (transposed) + accumulate e_sq partial
#pragma unroll
      for (int q = 0; q < 4; ++q) {
        float4 v = rb[q];
        esqa = fmaf(v.x, v.x, esqa); esqa = fmaf(v.y, v.y, esqa);
        esqa = fmaf(v.z, v.z, esqa); esqa = fmaf(v.w, v.w, esqa);
        Bs[par * 16 + q * 4 + 0][sm] = v.x;
        Bs[par * 16 + q * 4 + 1][sm] = v.y;
        Bs[par * 16 + q * 4 + 2][sm] = v.z;
        Bs[par * 16 + q * 4 + 3][sm] = v.w;
      }
      if (kc == 3) esqp[sm][par] = esqa;
      __syncthreads();
      // prefetch next chunk into registers (consumed next iteration)
      {
        const int t = mt * 4 + kc + 1;
        if (t < (M / 128) * 4) {
          const float* p = cbp + (size_t)(t >> 2) * (128 * E) + (t & 3) * 32;
#pragma unroll
          for (int q = 0; q < 4; ++q) rb[q] = *(const float4*)(p + q * 4);
        }
      }
      // compute: 32 k-iters, 32 FMA per k per thread
      const int kb = kc * 32;
#pragma unroll
      for (int k = 0; k < 32; ++k) {
        float a[4], b[8];
        *(float4*)&a[0] = *(const float4*)&As[kb + k][ty * 4];
        *(float4*)&b[0] = *(const float4*)&Bs[k][tx * 8];
        *(float4*)&b[4] = *(const float4*)&Bs[k][tx * 8 + 4];
#pragma unroll
        for (int i = 0; i < 4; ++i)
#pragma unroll
          for (int j = 0; j < 8; ++j) acc[i][j] = fmaf(a[i], b[j], acc[i][j]);
      }
    }
    // epilogue: merge argmin (m ascending within thread -> strict <)
#pragma unroll
    for (int j = 0; j < 8; ++j) {
      const int col = tx * 8 + j;
      const float es = esqp[col][0] + esqp[col][1];
      const int mg = mt * 128 + col;
#pragma unroll
      for (int i = 0; i < 4; ++i) {
        float s = fmaf(-2.0f, acc[i][j], es);
        if (s < bestv[i]) { bestv[i] = s; besti[i] = mg; }
      }
    }
  }

  // cross-thread reduction per row (alias scratch over As; As is dead)
  __syncthreads();
  float* redv = &As[0][0];          // 64*16 floats
  int*   redi = (int*)&As[32][0];   // 64*16 ints (8 KB offset, no overlap)
#pragma unroll
  for (int i = 0; i < 4; ++i) {
    redv[(ty * 4 + i) * 16 + tx] = bestv[i];
    redi[(ty * 4 + i) * 16 + tx] = besti[i];
  }
  __syncthreads();
  if (tid < 64) {
    float bv = 3.4e38f; int bi = 0x7fffffff;
    for (int x = 0; x < 16; ++x) {
      float v = redv[tid * 16 + x];
      int   id = redi[tid * 16 + x];
      if (v < bv || (v == bv && id < bi)) { bv = v; bi = id; }
    }
    idxo[c * BN + bn0 + tid] = bi;
  }
}

// ---------------------------------------------------------------------------
// K3: out[bn][v] = mean_c values[c][idx[c][bn]][v]
// one block per bn; thread t handles c = t; tree reduce.
// ---------------------------------------------------------------------------
__global__ __launch_bounds__(256) void k3_gather(const int* __restrict__ idxw,
                                                 const float* __restrict__ vals,
                                                 float* __restrict__ out) {
  const int bn = blockIdx.x;
  const int t  = threadIdx.x;   // = c
  __shared__ float red[256][V];
  const int id = idxw[t * BN + bn];
  const float* vp = vals + ((size_t)t * M + id) * V;
#pragma unroll
  for (int j = 0; j < V; ++j) red[t][j] = vp[j];
  __syncthreads();
  for (int s = 128; s > 0; s >>= 1) {
    if (t < s) {
#pragma unroll
      for (int j = 0; j < V; ++j) red[t][j] += red[t + s][j];
    }
    __syncthreads();
  }
  if (t < V) out[bn * V + t] = red[0][t] * (1.0f / 256.0f);
}

// ---------------------------------------------------------------------------
extern "C" void kernel_launch(void* const* d_in, const int* in_sizes, int n_in,
                              void* d_out, int out_size, void* d_ws, size_t ws_size,
                              hipStream_t stream) {
  const float* emb  = (const float*)d_in[0];  // (4,64,2048)
  const float* proj = (const float*)d_in[1];  // (256,2048,128)
  const float* cb   = (const float*)d_in[2];  // (256,4096,128)
  const float* vals = (const float*)d_in[3];  // (256,4096,10)
  float* out = (float*)d_out;                 // (4,64,10)

  float* xp   = (float*)d_ws;                               // 33,554,432 B
  int*   idxw = (int*)((char*)d_ws + (size_t)C * BN * E * 4); // +256 KB

  k1_xp    <<<dim3(2, C), 256, 0, stream>>>(emb, proj, xp);
  k2_argmin<<<dim3(4, C), 256, 0, stream>>>(xp, cb, idxw);
  k3_gather<<<BN, 256, 0, stream>>>(idxw, vals, out);
}